// Round 3
// baseline (830.920 us; speedup 1.0000x reference)
//
#include <hip/hip_runtime.h>
#include <math.h>

#define BATCH 512
#define ITERS 1000
#define PLEN 25      // iterations per phase
#define PHASES 40    // producer phase p covers k = 25p+1 .. 25p+25

typedef float f32x2 __attribute__((ext_vector_type(2)));
typedef float f32x4 __attribute__((ext_vector_type(4)));

// readlane requires a WAVE-UNIFORM lane index (compile-time constants below).
__device__ __forceinline__ float rdlane(float v, int l) {
  return __int_as_float(__builtin_amdgcn_readlane(__float_as_int(v), l));
}
__device__ __forceinline__ f32x2 fma2(f32x2 a, f32x2 b, f32x2 c) {
#if __has_builtin(__builtin_elementwise_fma)
  return __builtin_elementwise_fma(a, b, c);
#else
  f32x2 r; r.x = fmaf(a.x, b.x, c.x); r.y = fmaf(a.y, b.y, c.y); return r;
#endif
}

// sD row `lane` stored as 32 packed f32x2 (for v_pk_fma_f32). Element access
// for the setup code (all indices compile-time constants in unrolled loops):
#define DC(c) (((c) & 1) ? dcol2[(c) >> 1].y : dcol2[(c) >> 1].x)

// Register-resident Gauss-Jordan on [A|I] (32x64); lane holds column `lane`.
#define GJ32_REG(g)                                            \
  _Pragma("unroll")                                            \
  for (int k = 0; k < 32; ++k) {                               \
    float inv = 1.0f / rdlane(g[k], k);                        \
    g[k] *= inv;                                               \
    _Pragma("unroll")                                          \
    for (int ii = 0; ii < 32; ++ii) {                          \
      if (ii == k) continue;                                   \
      float f = rdlane(g[ii], k);                              \
      g[ii] = fmaf(-f, g[k], g[ii]);                           \
    }                                                          \
  }

// wave-1 body: Xs stores only (short chain, unroll 4 pipelines LDS latency)
#define STORE25(rx1, rx2, Xk)                                  \
  _Pragma("unroll 4")                                          \
  for (int u = 0; u < PLEN; ++u) {                             \
    float x1v  = (rx1)[u * 64 + lane];                         \
    float x2mb = (rx2)[u * 64 + lane];                         \
    (Xk)[u * 128 + lane] = x1v;                                \
    (Xk)[u * 128 + 64 + lane] = x2mb + bl;                     \
  }

// wave-2 body: primal GEMV only (unroll 2 overlaps b128 read latency)
#define PRIM25(rx2, obk)                                       \
  _Pragma("unroll 2")                                          \
  for (int u = 0; u < PLEN; ++u) {                             \
    const f32x4* tp = (const f32x4*)((rx2) + u * 64 + h * 32); \
    f32x2 pa = {0.f, 0.f}, pb = {0.f, 0.f};                    \
    _Pragma("unroll")                                          \
    for (int t = 0; t < 8; ++t) {                              \
      f32x4 tv = tp[t];                                        \
      pa = fma2(hv2[2*t],     tv.xy, pa);                      \
      pb = fma2(hv2[2*t + 1], tv.zw, pb);                      \
    }                                                          \
    float pr = (pa.x + pa.y) + (pb.x + pb.y);                  \
    pr += __shfl_xor(pr, 32);                                  \
    if (h == 0) (obk)[u * 32 + i] = pr;                        \
  }

// 3 waves: wave 0 = iterator (serial recurrence, broadcast x1 via uniform
// ds_read_b128 + packed FMAs). wave 1 = Xs stores. wave 2 = primal GEMV.
// v4 change vs v3: the consumer was the critical path (v0/v1/v2 all pinned
// near ~790-860 cyc/iter = consumer drain time; iterator changes barely
// moved the total). Splitting the consumer into two waves with unrolled,
// pipelined loops pushes the phase ceiling down to the iterator (~450-500).
__global__ __launch_bounds__(192, 1)
void fused_kernel(const float* __restrict__ q,
                  const float* __restrict__ bmat,
                  const float* __restrict__ P,
                  const float* __restrict__ H,
                  float* __restrict__ Xs,
                  float* __restrict__ out2) {
  __shared__ __align__(16) float stage[2112];        // wave 2: Hl 64x33 -> HT 32x66
  __shared__ __align__(16) float X1R[2][PLEN][64];   // ring: x1
  __shared__ __align__(16) float X2R[2][PLEN][64];   // ring: x2 - b

  const int tid = threadIdx.x;
  const int wv = tid >> 6;          // 0 = iterator, 1 = Xs stores, 2 = primal
  const int lane = tid & 63;
  const int row = blockIdx.x;
  const int i = lane & 31, h = lane >> 5;

  // ---- H row `lane` (waves 0 and 2 need it) ----
  float hreg[32];
  if (wv != 1) {
    const f32x4* hp = (const f32x4*)(H + lane * 32);
    #pragma unroll
    for (int j4 = 0; j4 < 8; ++j4) {
      f32x4 t = hp[j4];
      hreg[4*j4+0] = t.x; hreg[4*j4+1] = t.y; hreg[4*j4+2] = t.z; hreg[4*j4+3] = t.w;
    }
  }
  const float bl = bmat[row * 64 + lane];

  f32x2 dcol2[32]; float s = 0.f, mu = 0.f;       // iterator state
  f32x4 xb[16];                                   // broadcast x1 (iterator)
  float x1 = 0.f, x2 = 0.f;
  f32x2 hv2[16];                                  // wave-2 state (Hinv frags)
  float* Xp = Xs + (size_t)row * (ITERS + 1) * 128;
  float* ob = out2 + (size_t)row * (ITERS + 1) * 32;

  // ---------- wave-2 Hinv transpose (block-wide barriers B1..B3) ----------
  if (wv == 2) {
    #pragma unroll
    for (int j = 0; j < 32; ++j) stage[lane * 33 + j] = hreg[j];
  }
  __syncthreads();                                // B1
  float gB[32];
  if (wv == 2) {
    float htc[64];                                // htc[m] = H[m][i]
    #pragma unroll
    for (int m = 0; m < 64; ++m) htc[m] = stage[m * 33 + i];
    #pragma unroll
    for (int r = 0; r < 32; ++r) {
      float a0 = 0.f, a1 = 0.f;
      #pragma unroll
      for (int m = 0; m < 64; m += 2) {
        a0 = fmaf(rdlane(hreg[r], m),     htc[m],     a0);
        a1 = fmaf(rdlane(hreg[r], m + 1), htc[m + 1], a1);
      }
      float hth = a0 + a1;                        // (H^T H)[r][i]
      gB[r] = (lane < 32) ? hth : (((lane - 32) == r) ? 1.0f : 0.0f);
    }
    GJ32_REG(gB)
  }
  __syncthreads();                                // B2
  if (wv == 2) {
    #pragma unroll
    for (int r = 0; r < 32; ++r) {                // Hinv[r][lane] -> staging
      float a0 = 0.f, a1 = 0.f;
      #pragma unroll
      for (int c = 0; c < 32; c += 2) {
        a0 = fmaf(rdlane(gB[r], 32 + c),     hreg[c],     a0);
        a1 = fmaf(rdlane(gB[r], 32 + c + 1), hreg[c + 1], a1);
      }
      stage[r * 66 + lane] = a0 + a1;
    }
  }
  __syncthreads();                                // B3
  if (wv == 2) {
    #pragma unroll
    for (int t = 0; t < 16; ++t)                  // lane (h,i): Hinv[i][32h+2t..+1]
      hv2[t] = *(const f32x2*)&stage[i * 66 + 32 * h + 2 * t];
  }

  if (wv == 0) {
    // ---------- setup (registers only): P^-1, P^-1 H^T, D, lambda_max ----------
    float pht[32], acc;
    {
      float g[32];
      #pragma unroll
      for (int r = 0; r < 32; ++r) {
        float pv = P[r * 32 + i];
        g[r] = (lane < 32) ? pv : (((lane - 32) == r) ? 1.0f : 0.0f);
      }
      GJ32_REG(g)
      #pragma unroll
      for (int r = 0; r < 32; ++r) {      // (P^-1 H^T)[r][lane]
        float a0 = 0.f, a1 = 0.f;
        #pragma unroll
        for (int j = 0; j < 32; j += 2) {
          a0 = fmaf(rdlane(g[r], 32 + j),     hreg[j],     a0);
          a1 = fmaf(rdlane(g[r], 32 + j + 1), hreg[j + 1], a1);
        }
        pht[r] = a0 + a1;
      }
    }
    {
      const float* qp = q + row * 32;     // wave-uniform -> s_loads
      float a0 = 0.f, a1 = 0.f;
      #pragma unroll
      for (int r = 0; r < 32; r += 2) {
        a0 = fmaf(qp[r],     pht[r],     a0);
        a1 = fmaf(qp[r + 1], pht[r + 1], a1);
      }
      acc = a0 + a1;                      // (H P^-1 q)[lane]
    }
    #pragma unroll
    for (int r = 0; r < 64; ++r) {        // D[r][lane] (symmetric)
      float a0 = 0.f, a1 = 0.f;
      #pragma unroll
      for (int j = 0; j < 32; j += 2) {
        a0 = fmaf(rdlane(hreg[j],     r), pht[j],     a0);
        a1 = fmaf(rdlane(hreg[j + 1], r), pht[j + 1], a1);
      }
      float val = a0 + a1;
      if (r & 1) dcol2[r >> 1].y = val; else dcol2[r >> 1].x = val;
    }
    {
      float ecol[64];                     // E = D^2 (squares convergence rate)
      #pragma unroll
      for (int r = 0; r < 64; ++r) {
        float a0 = 0.f, a1 = 0.f;
        #pragma unroll
        for (int c = 0; c < 64; c += 2) {
          a0 = fmaf(rdlane(DC(r), c),     DC(c),     a0);
          a1 = fmaf(rdlane(DC(r), c + 1), DC(c + 1), a1);
        }
        ecol[r] = a0 + a1;
      }
      float v = 1.0f + 0.017f * (float)lane;
      #pragma unroll 1
      for (int t = 0; t < 112; ++t) {
        float a0 = 0.f, a1 = 0.f, a2 = 0.f, a3 = 0.f;
        #pragma unroll
        for (int c = 0; c < 64; c += 4) {
          a0 = fmaf(ecol[c+0], rdlane(v, c+0), a0);
          a1 = fmaf(ecol[c+1], rdlane(v, c+1), a1);
          a2 = fmaf(ecol[c+2], rdlane(v, c+2), a2);
          a3 = fmaf(ecol[c+3], rdlane(v, c+3), a3);
        }
        v = (a0 + a1) + (a2 + a3);
        if ((t & 7) == 7) {
          float n2 = v * v;
          #pragma unroll
          for (int m = 1; m < 64; m <<= 1) n2 += __shfl_xor(n2, m);
          v *= 1.0f / sqrtf(n2);
        }
      }
      float a0 = 0.f, a1 = 0.f, a2 = 0.f, a3 = 0.f;  // Rayleigh with D
      #pragma unroll
      for (int c = 0; c < 64; c += 4) {
        a0 = fmaf(DC(c+0), rdlane(v, c+0), a0);
        a1 = fmaf(DC(c+1), rdlane(v, c+1), a1);
        a2 = fmaf(DC(c+2), rdlane(v, c+2), a2);
        a3 = fmaf(DC(c+3), rdlane(v, c+3), a3);
      }
      float w = (a0 + a1) + (a2 + a3);
      float num = w * v, den = v * v;
      #pragma unroll
      for (int m = 1; m < 64; m <<= 1) {
        num += __shfl_xor(num, m);
        den += __shfl_xor(den, m);
      }
      s = den / num;                      // s = 1 / lambda_max(D)
    }
    mu = s * (acc - bl);
    #pragma unroll
    for (int t = 0; t < 32; ++t) dcol2[t] *= s;  // row `lane` of s*D, packed

    // ---- prologue: k = 1 directly (X0 = 0 -> x1 = mu, x2 = relu(-2 mu)) ----
    // Write ring row 0 of buffer 0, then issue the broadcast reads that
    // iteration u=1 will consume (same-wave DS ops are in-order: RAW safe).
    x1 = mu;
    x2 = fmaxf(-2.0f * mu, 0.f);
    X1R[0][0][lane] = x1;
    X2R[0][0][lane] = x2 - bl;
    {
      const f32x4* bp = (const f32x4*)&X1R[0][0][0];  // uniform addr: broadcast
      #pragma unroll
      for (int t = 0; t < 16; ++t) xb[t] = bp[t];
    }
  }

  // ---------- main loop: 40 phases x 25 iterations ----------
  #pragma unroll 1
  for (int p = 0; p < PHASES; ++p) {
    if (wv == 0) {
      float* rx1 = &X1R[p & 1][0][0];
      float* rx2 = &X2R[p & 1][0][0];
      #pragma unroll 1
      for (int u = (p == 0) ? 1 : 0; u < PLEN; ++u) {
        float ta = fmaf(s, x2, mu);
        f32x2 A0 = {0.f, 0.f}, A1 = {0.f, 0.f};
        f32x2 A2 = {0.f, 0.f}, A3 = {0.f, 0.f};
        // 32 packed FMAs: sD (packed pairs) * broadcast x1 (from LDS ring)
        #pragma unroll
        for (int t = 0; t < 16; t += 2) {
          A0 = fma2(dcol2[2*t + 0], xb[t].xy,     A0);
          A1 = fma2(dcol2[2*t + 1], xb[t].zw,     A1);
          A2 = fma2(dcol2[2*t + 2], xb[t + 1].xy, A2);
          A3 = fma2(dcol2[2*t + 3], xb[t + 1].zw, A3);
        }
        f32x2 R = (A0 + A1) + (A2 + A3);
        float x1n = (R.x + R.y) + ta;
        rx1[u * 64 + lane] = x1n;
        // issue next iteration's broadcast reads NOW (in-order DS pipe sees
        // the ring write above first); x2 tail below hides part of the latency
        {
          const f32x4* bp = (const f32x4*)(rx1 + u * 64);
          #pragma unroll
          for (int t = 0; t < 16; ++t) xb[t] = bp[t];
        }
        float x2n = fmaxf(fmaf(-2.0f, x1n, x1 + x2), 0.f);
        rx2[u * 64 + lane] = x2n - bl;
        x1 = x1n; x2 = x2n;
      }
    } else if (p == 0) {
      if (wv == 1) {
        // k = 0: X0 = 0 stores
        Xp[lane] = 0.f;
        Xp[64 + lane] = 0.f;
      } else {
        // k = 0: primal_0 = Hinv @ (-b)
        f32x2 pa = {0.f, 0.f}, pb = {0.f, 0.f};
        #pragma unroll
        for (int t = 0; t < 8; ++t) {
          f32x2 ta, tb;
          ta.x = -__shfl(bl, 32*h + 4*t + 0, 64);
          ta.y = -__shfl(bl, 32*h + 4*t + 1, 64);
          tb.x = -__shfl(bl, 32*h + 4*t + 2, 64);
          tb.y = -__shfl(bl, 32*h + 4*t + 3, 64);
          pa = fma2(hv2[2*t],     ta, pa);
          pb = fma2(hv2[2*t + 1], tb, pb);
        }
        float pr = (pa.x + pa.y) + (pb.x + pb.y);
        pr += __shfl_xor(pr, 32);
        if (h == 0) ob[i] = pr;
      }
    } else {
      const int k0 = PLEN * (p - 1) + 1;
      if (wv == 1) {
        STORE25(&X1R[(p - 1) & 1][0][0], &X2R[(p - 1) & 1][0][0],
                Xp + (size_t)k0 * 128)
      } else {
        PRIM25(&X2R[(p - 1) & 1][0][0], ob + (size_t)k0 * 32)
      }
    }
    __syncthreads();                      // all 3 waves, every phase
  }

  // tail: phase 39 data (buffer 1), k = 976..1000
  if (wv == 1) {
    const int k0 = PLEN * (PHASES - 1) + 1;
    STORE25(&X1R[1][0][0], &X2R[1][0][0], Xp + (size_t)k0 * 128)
  } else if (wv == 2) {
    const int k0 = PLEN * (PHASES - 1) + 1;
    PRIM25(&X2R[1][0][0], ob + (size_t)k0 * 32)
  }
}

extern "C" void kernel_launch(void* const* d_in, const int* in_sizes, int n_in,
                              void* d_out, int out_size, void* d_ws, size_t ws_size,
                              hipStream_t stream) {
  (void)in_sizes; (void)n_in; (void)out_size; (void)d_ws; (void)ws_size;
  const float* q = (const float*)d_in[0];
  const float* b = (const float*)d_in[1];
  const float* P = (const float*)d_in[2];
  const float* H = (const float*)d_in[3];
  float* Xs = (float*)d_out;
  float* out2 = Xs + (size_t)BATCH * (ITERS + 1) * 128;

  fused_kernel<<<BATCH, 192, 0, stream>>>(q, b, P, H, Xs, out2);
}